// Round 1
// 491.623 us; speedup vs baseline: 1.0878x; 1.0878x over previous
//
#include <hip/hip_runtime.h>
#include <math.h>

// LGTCN layer on MI355X — round 4: launch-graph compaction + fusion.
// 18 dispatches -> 9 per iteration:
//  - convS folded into diffuseA (convert S fp32->bf16 on first touch and
//    write-through SbT for the later passes): deletes the 100.7 MB SbT
//    re-read and one launch.
//  - reduce + update + pack fused into a single 256-thread kernel per step:
//    split-K Yp partials are summed straight into LDS bf16 MFMA fragments,
//    and the bf16 x-tile pack (xtT) is produced from the update's own
//    registers through LDS. Removes 4 reduce + 3 pack launches, the
//    YuT/YxT global round-trips, and lifts the update from 1 wave/CU to
//    4 waves/CU (4 waves e-split over the 64 output features).
// n_steps fixed at 4 by setup_inputs().

typedef unsigned short u16;
typedef unsigned int u32;
typedef __attribute__((ext_vector_type(8))) short short8;   // 8 bf16
typedef __attribute__((ext_vector_type(4))) float f32x4;

#define NN 4096
#define HD 64
#define KB32 128          // NN/32
#define DT_C 0.05f

__device__ __forceinline__ u16 f2bf(float f) {
    u32 u = __float_as_uint(f);
    u += 0x7FFFu + ((u >> 16) & 1u);   // RNE
    return (u16)(u >> 16);
}
__device__ __forceinline__ u32 pk2(float a, float b) {
    return (u32)f2bf(a) | ((u32)f2bf(b) << 16);
}

// ---------------- zprep: u,x fp32 [N][64] -> utT/xtT tiled; + WtT ----------------
// ztT[(kb*64 + e)*32 + kw] = z[kb*32 + kw][e]
__global__ __launch_bounds__(256) void zprep_kernel(
    const float* __restrict__ u, const float* __restrict__ x,
    const float* __restrict__ WAh, const float* __restrict__ WAs,
    const float* __restrict__ WBh, const float* __restrict__ WBs,
    u16* __restrict__ utT, u16* __restrict__ xtT, u16* __restrict__ WtT)
{
    const int b = blockIdx.x;
    const int t = threadIdx.x;
    if (b < 256) {
        const float* z = (b < 128) ? u : x;
        u16* ztT = (b < 128) ? utT : xtT;
        const int kb = b & 127, n0 = kb * 32;
        __shared__ __align__(16) u16 tile[64][40];   // [e][kw]
        const int nl = t >> 3, c0 = (t & 7) * 8;
        const float* src = z + (size_t)(n0 + nl) * HD + c0;
        float4 f0 = ((const float4*)src)[0];
        float4 f1 = ((const float4*)src)[1];
        tile[c0 + 0][nl] = f2bf(f0.x); tile[c0 + 1][nl] = f2bf(f0.y);
        tile[c0 + 2][nl] = f2bf(f0.z); tile[c0 + 3][nl] = f2bf(f0.w);
        tile[c0 + 4][nl] = f2bf(f1.x); tile[c0 + 5][nl] = f2bf(f1.y);
        tile[c0 + 6][nl] = f2bf(f1.z); tile[c0 + 7][nl] = f2bf(f1.w);
        __syncthreads();
        const int e = t >> 2, kw0 = (t & 3) * 8;
        short8 v = *(const short8*)&tile[e][kw0];
        *(short8*)(ztT + ((size_t)kb * 64 + e) * 32 + kw0) = v;
    } else {
        // WtT[((mat*6 + s)*64 + e)*32 + kw] = W[mat][kp>>6][kp&63][e], kp=s*32+kw
        for (int f = t; f < 4 * 6 * 64 * 32; f += 256) {
            int mat = f / 12288, r = f % 12288;
            int s = r / 2048, r2 = r % 2048;
            int e = r2 >> 5, kw = r2 & 31;
            int kp = s * 32 + kw, tap = kp >> 6, d = kp & 63;
            const float* Wm = (mat == 0) ? WAh : (mat == 1) ? WAs : (mat == 2) ? WBh : WBs;
            WtT[f] = f2bf(Wm[((size_t)tap * HD + d) * HD + e]);
        }
    }
}

// ---------------- pass-A diffusion fused with S conversion ----------------
// Reads S fp32 row-major, converts to bf16 in-register (feeds MFMA A-frags)
// and writes SbT[((tap*128+kb)*4096 + n)*32 + kw] for the later passes.
// Each (tap, kb, row) is touched by exactly one block -> one conversion.
// grid (32, KS_A, 3); iters = 128/KS_A kb-blocks per block.
__global__ __launch_bounds__(256) void diffuseA_kernel(
    const float* __restrict__ S, const u16* __restrict__ utT,
    const u16* __restrict__ xtT, u16* __restrict__ SbT,
    float* __restrict__ Yp, int iters)
{
    const int t = threadIdx.x;
    const int tap = blockIdx.z;
    const int row0 = blockIdx.x * 128;
    const int kb0 = blockIdx.y * iters;
    const int w = t >> 6, lane = t & 63, l15 = lane & 15, quad = lane >> 4;

    const int r0 = row0 + w * 32 + l15;                     // a0 rows; a1 = +16
    const float* Sb = S + ((size_t)tap * NN + r0) * NN + quad * 8;
    u16* Wb = SbT + (((size_t)tap * KB32) * NN + r0) * 32 + quad * 8;

    f32x4 z4 = {0.f, 0.f, 0.f, 0.f};
    f32x4 acc[2][2][4];   // [src][rt][ct]
    #pragma unroll
    for (int s = 0; s < 2; ++s)
        #pragma unroll
        for (int i = 0; i < 2; ++i)
            #pragma unroll
            for (int j = 0; j < 4; ++j) acc[s][i][j] = z4;

    #pragma unroll 2
    for (int it = 0; it < iters; ++it) {
        const int kb = kb0 + it;
        const float* sp0 = Sb + (size_t)kb * 32;
        const float* sp1 = sp0 + (size_t)16 * NN;
        float4 f0 = ((const float4*)sp0)[0];
        float4 f1 = ((const float4*)sp0)[1];
        float4 g0 = ((const float4*)sp1)[0];
        float4 g1 = ((const float4*)sp1)[1];
        union U { uint4 u4; short8 s8; };
        U A0, A1;
        A0.u4.x = pk2(f0.x, f0.y); A0.u4.y = pk2(f0.z, f0.w);
        A0.u4.z = pk2(f1.x, f1.y); A0.u4.w = pk2(f1.z, f1.w);
        A1.u4.x = pk2(g0.x, g0.y); A1.u4.y = pk2(g0.z, g0.w);
        A1.u4.z = pk2(g1.x, g1.y); A1.u4.w = pk2(g1.z, g1.w);
        u16* wb = Wb + (size_t)kb * (NN * 32);
        *(uint4*)wb = A0.u4;
        *(uint4*)(wb + 16 * 32) = A1.u4;
        #pragma unroll
        for (int ct = 0; ct < 4; ++ct) {
            const size_t bo = ((size_t)kb * 64 + ct * 16 + l15) * 32 + quad * 8;
            short8 bu = *(const short8*)(utT + bo);
            short8 bx = *(const short8*)(xtT + bo);
            acc[0][0][ct] = __builtin_amdgcn_mfma_f32_16x16x32_bf16(A0.s8, bu, acc[0][0][ct], 0, 0, 0);
            acc[0][1][ct] = __builtin_amdgcn_mfma_f32_16x16x32_bf16(A1.s8, bu, acc[0][1][ct], 0, 0, 0);
            acc[1][0][ct] = __builtin_amdgcn_mfma_f32_16x16x32_bf16(A0.s8, bx, acc[1][0][ct], 0, 0, 0);
            acc[1][1][ct] = __builtin_amdgcn_mfma_f32_16x16x32_bf16(A1.s8, bx, acc[1][1][ct], 0, 0, 0);
        }
    }
    // C/D: col = lane&15, row = quad*4 + reg
    #pragma unroll
    for (int s = 0; s < 2; ++s) {
        float* yb = Yp + ((size_t)((blockIdx.y * 3 + tap) * 2 + s) * NN + row0) * HD;
        #pragma unroll
        for (int rt = 0; rt < 2; ++rt)
            #pragma unroll
            for (int ct = 0; ct < 4; ++ct)
                #pragma unroll
                for (int r = 0; r < 4; ++r)
                    yb[(size_t)(w * 32 + rt * 16 + quad * 4 + r) * HD + ct * 16 + l15] = acc[s][rt][ct][r];
    }
}

// ---------------- step diffusion: S @ x (unchanged) ----------------
__global__ __launch_bounds__(256) void diffuseS_kernel(
    const u16* __restrict__ SbT, const u16* __restrict__ xtT,
    float* __restrict__ Yp, int iters)
{
    const int t = threadIdx.x;
    const int tap = blockIdx.z;
    const int row0 = blockIdx.x * 128;
    const int kb0 = blockIdx.y * iters;
    const int w = t >> 6, lane = t & 63, l15 = lane & 15, quad = lane >> 4;

    const u16* A0 = SbT + (((size_t)(tap * KB32) * NN + row0 + w * 32 + l15) * 32) + quad * 8;
    const size_t arowstride = (size_t)NN * 32;

    f32x4 z4 = {0.f, 0.f, 0.f, 0.f};
    f32x4 acc[2][4];
    #pragma unroll
    for (int i = 0; i < 2; ++i)
        #pragma unroll
        for (int j = 0; j < 4; ++j) acc[i][j] = z4;

    #pragma unroll 2
    for (int it = 0; it < iters; ++it) {
        const int kb = kb0 + it;
        const u16* ab = A0 + (size_t)kb * arowstride;
        short8 a0 = *(const short8*)(ab);
        short8 a1 = *(const short8*)(ab + 16 * 32);
        #pragma unroll
        for (int ct = 0; ct < 4; ++ct) {
            short8 bb = *(const short8*)(xtT + ((size_t)kb * 64 + ct * 16 + l15) * 32 + quad * 8);
            acc[0][ct] = __builtin_amdgcn_mfma_f32_16x16x32_bf16(a0, bb, acc[0][ct], 0, 0, 0);
            acc[1][ct] = __builtin_amdgcn_mfma_f32_16x16x32_bf16(a1, bb, acc[1][ct], 0, 0, 0);
        }
    }
    float* yb = Yp + ((size_t)(blockIdx.y * 3 + tap) * NN + row0) * HD;
    #pragma unroll
    for (int rt = 0; rt < 2; ++rt)
        #pragma unroll
        for (int ct = 0; ct < 4; ++ct)
            #pragma unroll
            for (int r = 0; r < 4; ++r)
                yb[(size_t)(w * 32 + rt * 16 + quad * 4 + r) * HD + ct * 16 + l15] = acc[rt][ct][r];
}

// ---------------- fused reduce + tap-GEMM + ODE + pack (steps 2..4) ----------------
// Block = 256 thr = 4 waves, 16 rows. Wave wv computes e = wv*16..+16.
// Phase 1: sum KS split-K Yp partials -> bf16 MFMA A-fragments in LDS.
// Phase 2: 6-step K-loop MFMA vs WtT, ODE epilogue, xn fp32 + xtT bf16 pack.
__global__ __launch_bounds__(256) void update_step_kernel(
    const float* __restrict__ Yp, int KS, const u16* __restrict__ WtT,
    const float* __restrict__ bx, const float* __restrict__ bvec,
    const float* __restrict__ fu, const float* __restrict__ sc,
    const float* __restrict__ xc, float* __restrict__ xn,
    u16* __restrict__ xtT, int do_pack)
{
    __shared__ __align__(16) u16 yt[6][16][56];   // [s][nloc][kw], pad 56 -> 2-way banks
    __shared__ __align__(16) u16 pkt[64][24];     // [e][nloc] bf16 pack staging
    const int t = threadIdx.x;
    const int n0 = blockIdx.x * 16;

    // Phase 1: 384 tasks = tap(3) x nloc(16) x d8(8)
    for (int f = t; f < 384; f += 256) {
        const int tap = f >> 7;
        const int r = f & 127;
        const int nl = r >> 3, d8 = r & 7, d0 = d8 * 8;
        const float* p = Yp + ((size_t)tap * NN + n0 + nl) * HD + d0;
        const size_t kstride = (size_t)3 * NN * HD;
        float4 s0 = {0.f, 0.f, 0.f, 0.f}, s1 = {0.f, 0.f, 0.f, 0.f};
        for (int y = 0; y < KS; ++y) {
            float4 v0 = ((const float4*)(p + (size_t)y * kstride))[0];
            float4 v1 = ((const float4*)(p + (size_t)y * kstride))[1];
            s0.x += v0.x; s0.y += v0.y; s0.z += v0.z; s0.w += v0.w;
            s1.x += v1.x; s1.y += v1.y; s1.z += v1.z; s1.w += v1.w;
        }
        uint4 o;
        o.x = pk2(s0.x, s0.y); o.y = pk2(s0.z, s0.w);
        o.z = pk2(s1.x, s1.y); o.w = pk2(s1.z, s1.w);
        const int s = tap * 2 + (d8 >> 2), kw0 = (d8 & 3) * 8;
        *(uint4*)&yt[s][nl][kw0] = o;
    }
    __syncthreads();

    const int wv = t >> 6, lane = t & 63, l15 = lane & 15, quad = lane >> 4;
    f32x4 z4 = {0.f, 0.f, 0.f, 0.f};
    f32x4 aF = z4, aG = z4;
    #pragma unroll
    for (int s = 0; s < 6; ++s) {
        short8 a = *(const short8*)&yt[s][l15][quad * 8];
        const size_t wo = ((size_t)s * 64 + wv * 16 + l15) * 32 + quad * 8;
        short8 bF = *(const short8*)(WtT + wo);                 // WA_hat
        short8 bG = *(const short8*)(WtT + wo + 12288);         // WA_state
        aF = __builtin_amdgcn_mfma_f32_16x16x32_bf16(a, bF, aF, 0, 0, 0);
        aG = __builtin_amdgcn_mfma_f32_16x16x32_bf16(a, bG, aG, 0, 0, 0);
    }
    const int e = wv * 16 + l15;
    const float bxv = bx[e], bbv = bvec[e];
    float xos[4];
    #pragma unroll
    for (int r = 0; r < 4; ++r) {
        const int n = n0 + quad * 4 + r;
        const size_t o = (size_t)n * HD + e;
        float ff = fmaxf(aF[r] + bxv, 0.f) + fu[o];
        float xv = xc[o];
        float dx = -(bbv + ff) * xv - aG[r] + ff * sc[o];
        float xo = fminf(fmaxf(xv + DT_C * dx, -1.f), 1.f);
        xn[o] = xo;
        xos[r] = xo;
    }
    if (do_pack) {
        uint2 pv;
        pv.x = pk2(xos[0], xos[1]);
        pv.y = pk2(xos[2], xos[3]);
        *(uint2*)&pkt[e][quad * 4] = pv;
        __syncthreads();
        if (t < 128) {
            const int ee = t >> 1, g = t & 1;
            short8 v = *(const short8*)&pkt[ee][g * 8];
            const int kb = n0 >> 5;
            const int kwb = (n0 & 31) + g * 8;
            *(short8*)(xtT + ((size_t)kb * 64 + ee) * 32 + kwb) = v;
        }
    }
}

// ---------------- fused update1: reduce(u,x) + fu/sigma_c + step 1 + pack ----------------
__global__ __launch_bounds__(256) void update1_kernel(
    const float* __restrict__ Yp, int KS, const u16* __restrict__ WtT,
    const float* __restrict__ bx, const float* __restrict__ bu,
    const float* __restrict__ bvec, const float* __restrict__ x0,
    float* __restrict__ fu, float* __restrict__ sc, float* __restrict__ x1,
    u16* __restrict__ xtT)
{
    __shared__ __align__(16) u16 yt[2][6][16][56];   // [src][s][nloc][kw], src 0=u 1=x
    __shared__ __align__(16) u16 pkt[64][24];
    const int t = threadIdx.x;
    const int n0 = blockIdx.x * 16;

    // Phase 1: 768 tasks = src(2) x tap(3) x nloc(16) x d8(8)
    #pragma unroll
    for (int ff = 0; ff < 3; ++ff) {
        const int f = t + ff * 256;
        const int src = f / 384;
        const int r3 = f - src * 384;
        const int tap = r3 >> 7;
        const int r = r3 & 127;
        const int nl = r >> 3, d8 = r & 7, d0 = d8 * 8;
        // slice = (y*3 + tap)*2 + src
        const float* p = Yp + (((size_t)(tap * 2 + src)) * NN + n0 + nl) * HD + d0;
        const size_t kstride = (size_t)6 * NN * HD;
        float4 s0 = {0.f, 0.f, 0.f, 0.f}, s1 = {0.f, 0.f, 0.f, 0.f};
        for (int y = 0; y < KS; ++y) {
            float4 v0 = ((const float4*)(p + (size_t)y * kstride))[0];
            float4 v1 = ((const float4*)(p + (size_t)y * kstride))[1];
            s0.x += v0.x; s0.y += v0.y; s0.z += v0.z; s0.w += v0.w;
            s1.x += v1.x; s1.y += v1.y; s1.z += v1.z; s1.w += v1.w;
        }
        uint4 o;
        o.x = pk2(s0.x, s0.y); o.y = pk2(s0.z, s0.w);
        o.z = pk2(s1.x, s1.y); o.w = pk2(s1.z, s1.w);
        const int s = tap * 2 + (d8 >> 2), kw0 = (d8 & 3) * 8;
        *(uint4*)&yt[src][s][nl][kw0] = o;
    }
    __syncthreads();

    const int wv = t >> 6, lane = t & 63, l15 = lane & 15, quad = lane >> 4;
    f32x4 z4 = {0.f, 0.f, 0.f, 0.f};
    f32x4 aF = z4, aG = z4, aFu = z4, aSc = z4;
    #pragma unroll
    for (int s = 0; s < 6; ++s) {
        short8 au = *(const short8*)&yt[0][s][l15][quad * 8];
        short8 ax = *(const short8*)&yt[1][s][l15][quad * 8];
        const size_t wo = ((size_t)s * 64 + wv * 16 + l15) * 32 + quad * 8;
        short8 bF  = *(const short8*)(WtT + wo);                 // WA_hat
        short8 bG  = *(const short8*)(WtT + wo + 12288);         // WA_state
        short8 bFu = *(const short8*)(WtT + wo + 2 * 12288);     // WB_hat
        short8 bSc = *(const short8*)(WtT + wo + 3 * 12288);     // WB_state
        aF  = __builtin_amdgcn_mfma_f32_16x16x32_bf16(ax, bF,  aF,  0, 0, 0);
        aG  = __builtin_amdgcn_mfma_f32_16x16x32_bf16(ax, bG,  aG,  0, 0, 0);
        aFu = __builtin_amdgcn_mfma_f32_16x16x32_bf16(au, bFu, aFu, 0, 0, 0);
        aSc = __builtin_amdgcn_mfma_f32_16x16x32_bf16(au, bSc, aSc, 0, 0, 0);
    }
    const int e = wv * 16 + l15;
    const float bxv = bx[e], buv = bu[e], bbv = bvec[e];
    float xos[4];
    #pragma unroll
    for (int r = 0; r < 4; ++r) {
        const int n = n0 + quad * 4 + r;
        const size_t o = (size_t)n * HD + e;
        float fuv = fmaxf(aFu[r] + buv, 0.f);
        float scv = tanhf(aSc[r]);
        float ff = fmaxf(aF[r] + bxv, 0.f) + fuv;
        float xv = x0[o];
        float dx = -(bbv + ff) * xv - aG[r] + ff * scv;
        float xo = fminf(fmaxf(xv + DT_C * dx, -1.f), 1.f);
        fu[o] = fuv; sc[o] = scv; x1[o] = xo;
        xos[r] = xo;
    }
    {
        uint2 pv;
        pv.x = pk2(xos[0], xos[1]);
        pv.y = pk2(xos[2], xos[3]);
        *(uint2*)&pkt[e][quad * 4] = pv;
        __syncthreads();
        if (t < 128) {
            const int ee = t >> 1, g = t & 1;
            short8 v = *(const short8*)&pkt[ee][g * 8];
            const int kb = n0 >> 5;
            const int kwb = (n0 & 31) + g * 8;
            *(short8*)(xtT + ((size_t)kb * 64 + ee) * 32 + kwb) = v;
        }
    }
}

extern "C" void kernel_launch(void* const* d_in, const int* in_sizes, int n_in,
                              void* d_out, int out_size, void* d_ws, size_t ws_size,
                              hipStream_t stream) {
    const float* x   = (const float*)d_in[0];
    const float* u   = (const float*)d_in[1];
    const float* S   = (const float*)d_in[2];
    const float* WAh = (const float*)d_in[3];
    const float* WBh = (const float*)d_in[4];
    const float* WAs = (const float*)d_in[5];
    const float* WBs = (const float*)d_in[6];
    const float* bx  = (const float*)d_in[7];
    const float* bu  = (const float*)d_in[8];
    const float* bvec= (const float*)d_in[9];
    float* out = (float*)d_out;

    const size_t sbf_bytes = (size_t)3 * NN * NN * 2;          // 100.7 MB
    const size_t slice = (size_t)NN * HD * 4;                  // 1 MB
    const size_t rest = 2 * 524288 + 98304 + 4 * 1048576;
    int KS_A = 4, KS_S = 8, nslice = 24;
    if (ws_size < sbf_bytes + 24 * slice + rest) { KS_A = 2; KS_S = 4; nslice = 12; }
    if (ws_size < sbf_bytes + 12 * slice + rest) { KS_A = 1; KS_S = 2; nslice = 6; }

    char* p = (char*)d_ws;
    u16* SbT  = (u16*)p;         p += sbf_bytes;
    float* Yp = (float*)p;       p += (size_t)nslice * slice;
    u16* utT  = (u16*)p;         p += 524288;
    u16* xtT  = (u16*)p;         p += 524288;
    u16* WtT  = (u16*)p;         p += 98304;
    float* fu = (float*)p;       p += 1048576;
    float* sc = (float*)p;       p += 1048576;
    float* xA = (float*)p;       p += 1048576;
    float* xB = (float*)p;       p += 1048576;

    zprep_kernel<<<257, 256, 0, stream>>>(u, x, WAh, WAs, WBh, WBs, utT, xtT, WtT);

    // Pass A: convert S on first touch, diffuse [u | x0], write SbT through
    diffuseA_kernel<<<dim3(32, KS_A, 3), 256, 0, stream>>>(S, utT, xtT, SbT, Yp, KB32 / KS_A);
    update1_kernel<<<256, 256, 0, stream>>>(Yp, KS_A, WtT, bx, bu, bvec, x, fu, sc, xA, xtT);

    // Steps 2..4
    diffuseS_kernel<<<dim3(32, KS_S, 3), 256, 0, stream>>>(SbT, xtT, Yp, KB32 / KS_S);
    update_step_kernel<<<256, 256, 0, stream>>>(Yp, KS_S, WtT, bx, bvec, fu, sc, xA, xB, xtT, 1);

    diffuseS_kernel<<<dim3(32, KS_S, 3), 256, 0, stream>>>(SbT, xtT, Yp, KB32 / KS_S);
    update_step_kernel<<<256, 256, 0, stream>>>(Yp, KS_S, WtT, bx, bvec, fu, sc, xB, xA, xtT, 1);

    diffuseS_kernel<<<dim3(32, KS_S, 3), 256, 0, stream>>>(SbT, xtT, Yp, KB32 / KS_S);
    update_step_kernel<<<256, 256, 0, stream>>>(Yp, KS_S, WtT, bx, bvec, fu, sc, xA, out, xtT, 0);
}